// Round 19
// baseline (297.389 us; speedup 1.0000x reference)
//
#include <hip/hip_runtime.h>

#define NPIX 4096
#define CCH  64
#define LOG2E 1.44269504088896f

typedef __attribute__((ext_vector_type(8))) short bf16x8;
typedef __attribute__((ext_vector_type(4))) float f32x4;

static __device__ __forceinline__ unsigned short f2bf(float f) {
    union { float f; unsigned u; } v; v.f = f;
    return (unsigned short)((v.u + 0x7FFFu + ((v.u >> 16) & 1u)) >> 16);
}
static __device__ __forceinline__ float bf2f_lo(unsigned u) {
    union { unsigned u; float f; } v; v.u = u << 16; return v.f;
}
static __device__ __forceinline__ float bf2f_hi(unsigned u) {
    union { unsigned u; float f; } v; v.u = u & 0xFFFF0000u; return v.f;
}

// LDS-only barrier: orders ds_read/ds_write across the block WITHOUT draining
// vmcnt. Safe: in-flight vmem is (a) attention stores no one reads (ABI
// guarantees completion before kernel-end signal), (b) K/V loads consumed
// same-wave via compiler waitcnts. (r12: -12.6 us vs __syncthreads)
#define LDS_BARRIER() do {                                             \
    asm volatile("s_waitcnt lgkmcnt(0)\n\ts_barrier" ::: "memory");    \
    __builtin_amdgcn_sched_barrier(0);                                 \
} while (0)

// Round 19 store/load-mode decomposition:
//   r13 (plain stores, plain loads): 210us -- regression == V-panel refetch
//     (512MB extra L3 traffic ~= +50us), NOT slow store drain: the fill
//     kernel drains plain stores at 6.7 TB/s vs our nt path's ~4.3.
//   r16 (nt stores, plain loads): 148.7us (best).
//   THIS (plain stores, nt K/V loads): stores get L2 write-back aggregation
//     (fill-kernel drain mode); K/V loads no-allocate -> V streams from L3,
//     immune to the write-stream's L2 eviction storm. Loads stay
//     compiler-tracked (no r17-class vmcnt hazard).

// ws layout (ushorts):
//   qf: [B][4096][8] bf16 @ 0         Q rows (PRE-SCALED by log2e), 16B each
//   kf: [B][4096][8] bf16 @ 262144    K rows, 16B each
//   vf: [B][128 kc][4 ct][64 lane][8] bf16 @ 524288
// vf is the exact B-fragment order for mfma_f32_16x16x32_bf16 (PV step):
//   B[k][col] = V[m = kc*32 + (lane>>4)*8 + j][c = ct*16 + (lane&15)]

// 4-way output split (r16: -6.3us): grid 2048, block (b, n-tile, sub) does
// outputs o in [sub*20, sub*20+20) for its 64-pixel tile.
__global__ __launch_bounds__(256) void qkv_kernel(
    const float* __restrict__ x,
    const float* __restrict__ Wq, const float* __restrict__ bq,
    const float* __restrict__ Wk, const float* __restrict__ bk,
    const float* __restrict__ Wv, const float* __restrict__ bv,
    unsigned short* __restrict__ ws)
{
    __shared__ float xs[64][64];              // [c][n_local]
    const int t   = threadIdx.x;
    const int bid = blockIdx.x;
    const int b   = bid >> 8;                 // 8 batches
    const int nt  = (bid >> 2) & 63;          // 64 n-tiles
    const int sub = bid & 3;                  // output sub-range
    const int n0  = nt << 6;
    const float* xb = x + ((size_t)b * CCH) * NPIX;

    #pragma unroll
    for (int ii = 0; ii < 16; ++ii) {
        int idx = t + (ii << 8);              // 0..4095
        int c = idx >> 6, nl = idx & 63;
        xs[c][nl] = xb[(size_t)c * NPIX + n0 + nl];
    }
    __syncthreads();

    const int nl = t & 63;
    // readfirstlane makes og provably wave-uniform -> W-row loads scalar.
    const int og = __builtin_amdgcn_readfirstlane(t >> 6);   // 0..3
    unsigned short* qf = ws;
    unsigned short* kf = ws + 262144;
    unsigned short* vf = ws + 524288;
    const int n = n0 + nl;

    // register-cache the pixel's channel vector
    float xr[64];
    #pragma unroll
    for (int c = 0; c < 64; ++c) xr[c] = xs[c][nl];

    #pragma unroll
    for (int oo = 0; oo < 5; ++oo) {
        const int o = sub * 20 + og * 5 + oo; // 0..79: 0-7 q, 8-15 k, 16-79 v
        const float* Wrow;
        float bias;
        if (o < 8)       { Wrow = Wq + o * CCH;        bias = bq[o]; }
        else if (o < 16) { Wrow = Wk + (o - 8) * CCH;  bias = bk[o - 8]; }
        else             { Wrow = Wv + (o - 16) * CCH; bias = bv[o - 16]; }
        float acc = bias;
        #pragma unroll
        for (int c = 0; c < CCH; ++c) acc += Wrow[c] * xr[c];
        if (o < 8)       qf[((size_t)b * NPIX + n) * 8 + o] = f2bf(acc * LOG2E);
        else if (o < 16) kf[((size_t)b * NPIX + n) * 8 + (o - 8)] = f2bf(acc);
        else {
            const int c  = o - 16;
            const int kc = n >> 5, r5 = n & 31;
            const int lane = ((r5 >> 3) << 4) | (c & 15);
            const size_t idx = ((((size_t)b * 128 + kc) * 4 + (c >> 4)) * 64 + lane) * 8 + (r5 & 7);
            vf[idx] = f2bf(acc);
        }
    }
}

// One block = 256 threads (4 waves) = 32 attention rows of one batch.
// r15/r16-proven structure. Energy TRANSPOSED via MFMA (Q pre-scaled by
// log2e): e' = mfma(A=K, B=Q); lane (c16,g) holds e' for row n=c16,
// m = mg+4g+r. Pass 1: s = sum 2^e'; lr = -log2(s) per lane.
// Main loop, double-buffered psb, 1 LDS-ONLY barrier per 256-m chunk:
//   PHASE_A(mc+1 -> nxt): P = exp2(e'+lr), bf16 pack -> swizzled psb.
//     K fragments via NT loads (no L2 allocate).
//   PHASE_B(mc, cur): PV MFMA; V fragments via NT loads (stream from L3,
//     immune to the attention write-stream's L2 evictions).
//   PHASE_S(mc, cur): wave w streams rows (i<<2)|w; ds_read_b64 swizzled,
//     1KB contiguous PLAIN store per wave-instruction (L2 write-back
//     aggregation = fill-kernel drain mode).
// Epilogue: attn_out / feature_delta / channel-LN fused.
// LDS = exactly 32768 B -> 5 blocks/CU.
__global__ __launch_bounds__(256) void attn_kernel(
    const float* __restrict__ x, const unsigned short* __restrict__ ws,
    const float* __restrict__ gamma_p,
    const float* __restrict__ ln_w, const float* __restrict__ ln_b,
    float* __restrict__ out, float* __restrict__ attn,
    float* __restrict__ fd_out, float* __restrict__ ao_out)
{
    __shared__ __align__(16) char psb0[16384];   // P chunk buf 0 (32 rows x 512B)
    __shared__ __align__(16) char psb1[16384];   // P chunk buf 1

    const int bid = blockIdx.x;
    const int wg  = ((bid & 7) << 7) | (bid >> 3);  // XCD-bijective: batch b -> XCD b
    const int b   = wg >> 7;
    const int n0  = (wg & 127) << 5;                // 32 rows

    const unsigned short* qf = ws;
    const unsigned short* kf = ws + 262144;
    const unsigned short* vf = ws + 524288;

    const int t   = threadIdx.x;
    const int l   = t & 63;
    const int w   = t >> 6;                       // wave id 0..3 = channel tile
    const int g   = l >> 4;                       // subgroup 0..3
    const int c16 = l & 15;

    const unsigned short* qfb = qf + ((size_t)b * NPIX + n0) * 8;
    const unsigned short* kfb = kf + (size_t)b * NPIX * 8;
    const unsigned short* vwave = vf + (size_t)b * 128 * 2048 + w * 512;

    const f32x4 zf = {0.f, 0.f, 0.f, 0.f};

    // Q as B-fragments (rows n0..+15 / +16..+31), lanes >= 16 zero (k pad)
    bf16x8 QB0 = {}, QB1 = {};
    if (l < 16) {
        QB0 = *(const bf16x8*)(qfb + l * 8);
        QB1 = *(const bf16x8*)(qfb + (16 + l) * 8);
    }

    // ---- pass 1: softmax denominators s = sum 2^e' ----
    float s0 = 0.f, s1 = 0.f;
    #pragma unroll 4
    for (int mt = 0; mt < 64; ++mt) {
        const int mbase = (w << 10) + (mt << 4);
        bf16x8 Kf = {};
        if (l < 16) Kf = __builtin_nontemporal_load(
                             (const bf16x8*)(kfb + (size_t)(mbase + l) * 8));
        f32x4 e0 = __builtin_amdgcn_mfma_f32_16x16x32_bf16(Kf, QB0, zf, 0, 0, 0);
        f32x4 e1 = __builtin_amdgcn_mfma_f32_16x16x32_bf16(Kf, QB1, zf, 0, 0, 0);
        #pragma unroll
        for (int r = 0; r < 4; ++r) {
            s0 += __builtin_amdgcn_exp2f(e0[r]);
            s1 += __builtin_amdgcn_exp2f(e1[r]);
        }
    }
    s0 += __shfl_xor(s0, 16); s0 += __shfl_xor(s0, 32);
    s1 += __shfl_xor(s1, 16); s1 += __shfl_xor(s1, 32);
    float lr0, lr1;
    {
        float* sred = (float*)psb0;               // [4 waves][32]
        if (l < 16) {
            sred[(w << 5) + l]      = s0;
            sred[(w << 5) + 16 + l] = s1;
        }
        __syncthreads();
        const float st0 = sred[c16]      + sred[32 + c16] + sred[64 + c16] + sred[96 + c16];
        const float st1 = sred[16 + c16] + sred[48 + c16] + sred[80 + c16] + sred[112 + c16];
        lr0 = -__builtin_amdgcn_logf(st0);        // v_log_f32 = log2
        lr1 = -__builtin_amdgcn_logf(st1);
        __syncthreads();                          // sred dead before PHASE_A reuses psb0
    }

    // ---- main loop ----
    const int swx = (c16 & 7) << 4;               // LDS swizzle (write & A-read)
    float* abase = attn + ((size_t)b * NPIX + n0) * NPIX + (l << 2);   // lane col = l*4

    f32x4 acc0 = zf, acc1 = zf;

#define PHASE_A(MC, BUF) do {                                                     \
    _Pragma("unroll")                                                             \
    for (int j = 0; j < 4; ++j) {                                                 \
        const int mg = ((MC) << 8) + (w << 6) + (j << 4);                         \
        bf16x8 Kf = {};                                                           \
        if (l < 16) Kf = __builtin_nontemporal_load(                              \
                             (const bf16x8*)(kfb + (size_t)(mg + l) * 8));        \
        f32x4 e0 = __builtin_amdgcn_mfma_f32_16x16x32_bf16(Kf, QB0, zf, 0, 0, 0); \
        f32x4 e1 = __builtin_amdgcn_mfma_f32_16x16x32_bf16(Kf, QB1, zf, 0, 0, 0); \
        uint2 pk0, pk1;                                                           \
        pk0.x = (unsigned)f2bf(__builtin_amdgcn_exp2f(e0[0] + lr0))               \
              | ((unsigned)f2bf(__builtin_amdgcn_exp2f(e0[1] + lr0)) << 16);      \
        pk0.y = (unsigned)f2bf(__builtin_amdgcn_exp2f(e0[2] + lr0))               \
              | ((unsigned)f2bf(__builtin_amdgcn_exp2f(e0[3] + lr0)) << 16);      \
        pk1.x = (unsigned)f2bf(__builtin_amdgcn_exp2f(e1[0] + lr1))               \
              | ((unsigned)f2bf(__builtin_amdgcn_exp2f(e1[1] + lr1)) << 16);      \
        pk1.y = (unsigned)f2bf(__builtin_amdgcn_exp2f(e1[2] + lr1))               \
              | ((unsigned)f2bf(__builtin_amdgcn_exp2f(e1[3] + lr1)) << 16);      \
        const int wo = ((w << 7) + (j << 5) + (g << 3)) ^ swx;                    \
        *(uint2*)((BUF) + c16 * 512 + wo)        = pk0;                           \
        *(uint2*)((BUF) + (16 + c16) * 512 + wo) = pk1;                           \
    }                                                                             \
} while (0)

#define PHASE_B(MC, BUF) do {                                                     \
    const unsigned short* vbase = vwave + ((size_t)(MC) << 14);                   \
    __builtin_amdgcn_s_setprio(1);                                                \
    _Pragma("unroll")                                                             \
    for (int kc8 = 0; kc8 < 8; ++kc8) {                                           \
        const int aoff = ((kc8 << 6) | (g << 4)) ^ swx;                           \
        const bf16x8 Bf = __builtin_nontemporal_load(                             \
            (const bf16x8*)(vbase + (size_t)kc8 * 2048 + l * 8));                 \
        const bf16x8 A0 = *(const bf16x8*)((BUF) + c16 * 512 + aoff);             \
        const bf16x8 A1 = *(const bf16x8*)((BUF) + c16 * 512 + 8192 + aoff);      \
        acc0 = __builtin_amdgcn_mfma_f32_16x16x32_bf16(A0, Bf, acc0, 0, 0, 0);    \
        acc1 = __builtin_amdgcn_mfma_f32_16x16x32_bf16(A1, Bf, acc1, 0, 0, 0);    \
    }                                                                             \
    __builtin_amdgcn_s_setprio(0);                                                \
} while (0)

// One row per wave-instruction: row = (i<<2)|w; lane l reads P[row][l*4..l*4+3]
// (bytes (l<<3)^((row&7)<<4), matching the write swizzle) and PLAIN-stores
// 16B at attention[row][mc*256 + l*4] -> 1024B contiguous run, L2 write-back.
#define PHASE_S(MC, BUF) do {                                                     \
    _Pragma("unroll")                                                             \
    for (int i = 0; i < 8; ++i) {                                                 \
        const int row   = (i << 2) | w;                                           \
        const int rbase = ((row & 15) << 9) + ((row >> 4) << 13);                 \
        const uint2 rv  = *(const uint2*)((BUF) + rbase                           \
                                          + ((l << 3) ^ ((row & 7) << 4)));       \
        f32x4 fv;                                                                 \
        fv[0] = bf2f_lo(rv.x); fv[1] = bf2f_hi(rv.x);                             \
        fv[2] = bf2f_lo(rv.y); fv[3] = bf2f_hi(rv.y);                             \
        *(f32x4*)(abase + (size_t)row * NPIX + ((MC) << 8)) = fv;                 \
    }                                                                             \
} while (0)

    PHASE_A(0, psb0);
    LDS_BARRIER();
    #pragma unroll 2
    for (int mc = 0; mc < 16; ++mc) {
        char* cur = (mc & 1) ? psb1 : psb0;
        char* nxt = (mc & 1) ? psb0 : psb1;
        if (mc < 15) PHASE_A(mc + 1, nxt);
        PHASE_B(mc, cur);
        PHASE_S(mc, cur);
        LDS_BARRIER();
    }
#undef PHASE_A
#undef PHASE_B
#undef PHASE_S

    // ---- epilogue: O_lds + LN scalars alias psb0 (dead after last barrier) ----
    float* O_lds = (float*)psb0;                   // [64][33] = 8448 B
    float* muv   = (float*)(psb0 + 8448);          // [32]
    float* rsg   = (float*)(psb0 + 8576);          // [32]
    {
        const int ch = (w << 4) + c16;
        const int r0 = g << 2;
        #pragma unroll
        for (int r = 0; r < 4; ++r) {
            O_lds[ch * 33 + r0 + r]      = acc0[r];
            O_lds[ch * 33 + 16 + r0 + r] = acc1[r];
        }
    }
    __syncthreads();

    const float gma = gamma_p[0];
    const float* xb = x + (size_t)b * CCH * NPIX + n0;
    {
        const int r = t >> 3, l8 = t & 7;
        float sum = 0.f, sum2 = 0.f;
        #pragma unroll
        for (int cc = 0; cc < 8; ++cc) {
            const int c = l8 + (cc << 3);
            const float pre = xb[(size_t)c * NPIX + r] + gma * O_lds[c * 33 + r];
            sum += pre; sum2 += pre * pre;
        }
        #pragma unroll
        for (int off = 1; off < 8; off <<= 1) {
            sum  += __shfl_xor(sum, off);
            sum2 += __shfl_xor(sum2, off);
        }
        if (l8 == 0) {
            const float m_ = sum * (1.f / 64.f);
            const float v_ = sum2 * (1.f / 64.f) - m_ * m_;
            muv[r] = m_;
            rsg[r] = rsqrtf(v_ + 1e-5f);
        }
    }
    __syncthreads();

    #pragma unroll
    for (int ii = 0; ii < 8; ++ii) {
        const int idx = t + (ii << 8);             // 0..2047 = 64c x 32n
        const int c = idx >> 5, nl = idx & 31;
        const float o   = O_lds[c * 33 + nl];
        const float fdv = gma * o;
        const float pre = xb[(size_t)c * NPIX + nl] + fdv;
        const float y   = (pre - muv[nl]) * rsg[nl] * ln_w[c] + ln_b[c];
        const size_t off = (size_t)b * CCH * NPIX + (size_t)c * NPIX + n0 + nl;
        ao_out[off] = o;
        fd_out[off] = fdv;
        out[off]    = y;
    }
}

extern "C" void kernel_launch(void* const* d_in, const int* in_sizes, int n_in,
                              void* d_out, int out_size, void* d_ws, size_t ws_size,
                              hipStream_t stream) {
    const float* x     = (const float*)d_in[0];
    const float* Wq    = (const float*)d_in[1];
    const float* bq    = (const float*)d_in[2];
    const float* Wk    = (const float*)d_in[3];
    const float* bk    = (const float*)d_in[4];
    const float* Wv    = (const float*)d_in[5];
    const float* bv    = (const float*)d_in[6];
    const float* gamma = (const float*)d_in[7];
    const float* lnw   = (const float*)d_in[8];
    const float* lnb   = (const float*)d_in[9];

    float* out  = (float*)d_out;                  // [8,64,64,64]
    float* attn = out + 2097152;                  // [8,4096,4096]
    float* fd   = out + 136314880;                // [8,64,64,64]
    float* ao   = out + 138412032;                // [8,64,64,64]
    unsigned short* ws = (unsigned short*)d_ws;   // 5 MB used

    qkv_kernel<<<2048, 256, 0, stream>>>(x, Wq, bq, Wk, bk, Wv, bv, ws);
    attn_kernel<<<1024, 256, 0, stream>>>(x, ws, gamma, lnw, lnb, out, attn, fd, ao);
}

// Round 20
// 145.044 us; speedup vs baseline: 2.0503x; 2.0503x over previous
//
#include <hip/hip_runtime.h>

#define NPIX 4096
#define CCH  64
#define LOG2E 1.44269504088896f

typedef __attribute__((ext_vector_type(8))) short bf16x8;
typedef __attribute__((ext_vector_type(4))) float f32x4;

static __device__ __forceinline__ unsigned short f2bf(float f) {
    union { float f; unsigned u; } v; v.f = f;
    return (unsigned short)((v.u + 0x7FFFu + ((v.u >> 16) & 1u)) >> 16);
}
static __device__ __forceinline__ float bf2f_lo(unsigned u) {
    union { unsigned u; float f; } v; v.u = u << 16; return v.f;
}
static __device__ __forceinline__ float bf2f_hi(unsigned u) {
    union { unsigned u; float f; } v; v.u = u & 0xFFFF0000u; return v.f;
}

// LDS-only barrier: orders ds_read/ds_write across the block WITHOUT draining
// vmcnt. Safe here because all in-flight vmem is (a) nt-stores to attention,
// which no one ever reads, or (b) K/V loads consumed same-wave via the
// compiler's own waitcnts. __syncthreads would stall every wave on store
// ACKs 16x per block for no correctness benefit. (r12: -12.6 us)
#define LDS_BARRIER() do {                                             \
    asm volatile("s_waitcnt lgkmcnt(0)\n\ts_barrier" ::: "memory");    \
    __builtin_amdgcn_sched_barrier(0);                                 \
} while (0)

// Store/load cache-mode decomposition (r13/r16/r18/r19): nt stores + plain
// loads is optimal. plain stores thrash L2 (V refetch, +52us); sc1 +9us;
// nt loads starve the K-broadcast/V-reuse cache hits (+148us).

// ws layout (ushorts):
//   qf: [B][4096][8] bf16 @ 0         Q rows (PRE-SCALED by log2e), 16B each
//   kf: [B][4096][8] bf16 @ 262144    K rows, 16B each
//   vf: [B][128 kc][4 ct][64 lane][8] bf16 @ 524288
// vf is the exact B-fragment order for mfma_f32_16x16x32_bf16 (PV step):
//   B[k][col] = V[m = kc*32 + (lane>>4)*8 + j][c = ct*16 + (lane&15)]

// 4-way output split (r16: -6.3us): grid 2048, block (b, n-tile, sub) does
// outputs o in [sub*20, sub*20+20) for its 64-pixel tile.
__global__ __launch_bounds__(256) void qkv_kernel(
    const float* __restrict__ x,
    const float* __restrict__ Wq, const float* __restrict__ bq,
    const float* __restrict__ Wk, const float* __restrict__ bk,
    const float* __restrict__ Wv, const float* __restrict__ bv,
    unsigned short* __restrict__ ws)
{
    __shared__ float xs[64][64];              // [c][n_local]
    const int t   = threadIdx.x;
    const int bid = blockIdx.x;
    const int b   = bid >> 8;                 // 8 batches
    const int nt  = (bid >> 2) & 63;          // 64 n-tiles
    const int sub = bid & 3;                  // output sub-range
    const int n0  = nt << 6;
    const float* xb = x + ((size_t)b * CCH) * NPIX;

    #pragma unroll
    for (int ii = 0; ii < 16; ++ii) {
        int idx = t + (ii << 8);              // 0..4095
        int c = idx >> 6, nl = idx & 63;
        xs[c][nl] = xb[(size_t)c * NPIX + n0 + nl];
    }
    __syncthreads();

    const int nl = t & 63;
    // readfirstlane makes og provably wave-uniform -> W-row loads scalar.
    const int og = __builtin_amdgcn_readfirstlane(t >> 6);   // 0..3
    unsigned short* qf = ws;
    unsigned short* kf = ws + 262144;
    unsigned short* vf = ws + 524288;
    const int n = n0 + nl;

    // register-cache the pixel's channel vector
    float xr[64];
    #pragma unroll
    for (int c = 0; c < 64; ++c) xr[c] = xs[c][nl];

    #pragma unroll
    for (int oo = 0; oo < 5; ++oo) {
        const int o = sub * 20 + og * 5 + oo; // 0..79: 0-7 q, 8-15 k, 16-79 v
        const float* Wrow;
        float bias;
        if (o < 8)       { Wrow = Wq + o * CCH;        bias = bq[o]; }
        else if (o < 16) { Wrow = Wk + (o - 8) * CCH;  bias = bk[o - 8]; }
        else             { Wrow = Wv + (o - 16) * CCH; bias = bv[o - 16]; }
        float acc = bias;
        #pragma unroll
        for (int c = 0; c < CCH; ++c) acc += Wrow[c] * xr[c];
        if (o < 8)       qf[((size_t)b * NPIX + n) * 8 + o] = f2bf(acc * LOG2E);
        else if (o < 16) kf[((size_t)b * NPIX + n) * 8 + (o - 8)] = f2bf(acc);
        else {
            const int c  = o - 16;
            const int kc = n >> 5, r5 = n & 31;
            const int lane = ((r5 >> 3) << 4) | (c & 15);
            const size_t idx = ((((size_t)b * 128 + kc) * 4 + (c >> 4)) * 64 + lane) * 8 + (r5 & 7);
            vf[idx] = f2bf(acc);
        }
    }
}

// One block = 256 threads (4 waves) = 32 attention rows of one batch.
// Proven structure (766 -> 148.7 us over 16 rounds). Energy TRANSPOSED via
// MFMA (Q pre-scaled by log2e): e' = mfma(A=K, B=Q); lane (c16,g) holds e'
// for row n=c16, m = mg+4g+r. Pass 1: s = sum 2^e'; lr = -log2(s) per lane.
// Main loop, double-buffered psb, 1 LDS-ONLY barrier per 256-m chunk:
//   PHASE_A(mc+1 -> nxt): P = exp2(e'+lr), bf16 pack -> swizzled psb.
//   PHASE_B(mc, cur): PV MFMA (wave = 16-channel tile).
//   PHASE_S(mc, cur): wave w streams rows (i<<2)|w; ds_read_b64 swizzled,
//     1KB contiguous nt-store per wave-instruction.
// Epilogue: attn_out / feature_delta / channel-LN fused.
// LDS = exactly 32768 B -> 5 blocks/CU.
__global__ __launch_bounds__(256) void attn_kernel(
    const float* __restrict__ x, const unsigned short* __restrict__ ws,
    const float* __restrict__ gamma_p,
    const float* __restrict__ ln_w, const float* __restrict__ ln_b,
    float* __restrict__ out, float* __restrict__ attn,
    float* __restrict__ fd_out, float* __restrict__ ao_out)
{
    __shared__ __align__(16) char psb0[16384];   // P chunk buf 0 (32 rows x 512B)
    __shared__ __align__(16) char psb1[16384];   // P chunk buf 1

    const int bid = blockIdx.x;
    const int wg  = ((bid & 7) << 7) | (bid >> 3);  // XCD-bijective: batch b -> XCD b
    const int b   = wg >> 7;
    const int n0  = (wg & 127) << 5;                // 32 rows

    const unsigned short* qf = ws;
    const unsigned short* kf = ws + 262144;
    const unsigned short* vf = ws + 524288;

    const int t   = threadIdx.x;
    const int l   = t & 63;
    const int w   = t >> 6;                       // wave id 0..3 = channel tile
    const int g   = l >> 4;                       // subgroup 0..3
    const int c16 = l & 15;

    const unsigned short* qfb = qf + ((size_t)b * NPIX + n0) * 8;
    const unsigned short* kfb = kf + (size_t)b * NPIX * 8;
    const unsigned short* vwave = vf + (size_t)b * 128 * 2048 + w * 512;

    const f32x4 zf = {0.f, 0.f, 0.f, 0.f};

    // Q as B-fragments (rows n0..+15 / +16..+31), lanes >= 16 zero (k pad)
    bf16x8 QB0 = {}, QB1 = {};
    if (l < 16) {
        QB0 = *(const bf16x8*)(qfb + l * 8);
        QB1 = *(const bf16x8*)(qfb + (16 + l) * 8);
    }

    // ---- pass 1: softmax denominators s = sum 2^e' ----
    float s0 = 0.f, s1 = 0.f;
    #pragma unroll 4
    for (int mt = 0; mt < 64; ++mt) {
        const int mbase = (w << 10) + (mt << 4);
        bf16x8 Kf = {};
        if (l < 16) Kf = *(const bf16x8*)(kfb + (size_t)(mbase + l) * 8);
        f32x4 e0 = __builtin_amdgcn_mfma_f32_16x16x32_bf16(Kf, QB0, zf, 0, 0, 0);
        f32x4 e1 = __builtin_amdgcn_mfma_f32_16x16x32_bf16(Kf, QB1, zf, 0, 0, 0);
        #pragma unroll
        for (int r = 0; r < 4; ++r) {
            s0 += __builtin_amdgcn_exp2f(e0[r]);
            s1 += __builtin_amdgcn_exp2f(e1[r]);
        }
    }
    s0 += __shfl_xor(s0, 16); s0 += __shfl_xor(s0, 32);
    s1 += __shfl_xor(s1, 16); s1 += __shfl_xor(s1, 32);
    float lr0, lr1;
    {
        float* sred = (float*)psb0;               // [4 waves][32]
        if (l < 16) {
            sred[(w << 5) + l]      = s0;
            sred[(w << 5) + 16 + l] = s1;
        }
        __syncthreads();
        const float st0 = sred[c16]      + sred[32 + c16] + sred[64 + c16] + sred[96 + c16];
        const float st1 = sred[16 + c16] + sred[48 + c16] + sred[80 + c16] + sred[112 + c16];
        lr0 = -__builtin_amdgcn_logf(st0);        // v_log_f32 = log2
        lr1 = -__builtin_amdgcn_logf(st1);
        __syncthreads();                          // sred dead before PHASE_A reuses psb0
    }

    // ---- main loop ----
    const int swx = (c16 & 7) << 4;               // LDS swizzle (write & A-read)
    float* abase = attn + ((size_t)b * NPIX + n0) * NPIX + (l << 2);   // lane col = l*4

    f32x4 acc0 = zf, acc1 = zf;

#define PHASE_A(MC, BUF) do {                                                     \
    _Pragma("unroll")                                                             \
    for (int j = 0; j < 4; ++j) {                                                 \
        const int mg = ((MC) << 8) + (w << 6) + (j << 4);                         \
        bf16x8 Kf = {};                                                           \
        if (l < 16) Kf = *(const bf16x8*)(kfb + (size_t)(mg + l) * 8);            \
        f32x4 e0 = __builtin_amdgcn_mfma_f32_16x16x32_bf16(Kf, QB0, zf, 0, 0, 0); \
        f32x4 e1 = __builtin_amdgcn_mfma_f32_16x16x32_bf16(Kf, QB1, zf, 0, 0, 0); \
        uint2 pk0, pk1;                                                           \
        pk0.x = (unsigned)f2bf(__builtin_amdgcn_exp2f(e0[0] + lr0))               \
              | ((unsigned)f2bf(__builtin_amdgcn_exp2f(e0[1] + lr0)) << 16);      \
        pk0.y = (unsigned)f2bf(__builtin_amdgcn_exp2f(e0[2] + lr0))               \
              | ((unsigned)f2bf(__builtin_amdgcn_exp2f(e0[3] + lr0)) << 16);      \
        pk1.x = (unsigned)f2bf(__builtin_amdgcn_exp2f(e1[0] + lr1))               \
              | ((unsigned)f2bf(__builtin_amdgcn_exp2f(e1[1] + lr1)) << 16);      \
        pk1.y = (unsigned)f2bf(__builtin_amdgcn_exp2f(e1[2] + lr1))               \
              | ((unsigned)f2bf(__builtin_amdgcn_exp2f(e1[3] + lr1)) << 16);      \
        const int wo = ((w << 7) + (j << 5) + (g << 3)) ^ swx;                    \
        *(uint2*)((BUF) + c16 * 512 + wo)        = pk0;                           \
        *(uint2*)((BUF) + (16 + c16) * 512 + wo) = pk1;                           \
    }                                                                             \
} while (0)

#define PHASE_B(MC, BUF) do {                                                     \
    const unsigned short* vbase = vwave + ((size_t)(MC) << 14);                   \
    __builtin_amdgcn_s_setprio(1);                                                \
    _Pragma("unroll")                                                             \
    for (int kc8 = 0; kc8 < 8; ++kc8) {                                           \
        const int aoff = ((kc8 << 6) | (g << 4)) ^ swx;                           \
        const bf16x8 Bf = *(const bf16x8*)(vbase + (size_t)kc8 * 2048 + l * 8);   \
        const bf16x8 A0 = *(const bf16x8*)((BUF) + c16 * 512 + aoff);             \
        const bf16x8 A1 = *(const bf16x8*)((BUF) + c16 * 512 + 8192 + aoff);      \
        acc0 = __builtin_amdgcn_mfma_f32_16x16x32_bf16(A0, Bf, acc0, 0, 0, 0);    \
        acc1 = __builtin_amdgcn_mfma_f32_16x16x32_bf16(A1, Bf, acc1, 0, 0, 0);    \
    }                                                                             \
    __builtin_amdgcn_s_setprio(0);                                                \
} while (0)

// One row per wave-instruction: row = (i<<2)|w; lane l reads P[row][l*4..l*4+3]
// (bytes (l<<3)^((row&7)<<4), matching the write swizzle) and stores 16B at
// attention[row][mc*256 + l*4] -> 64 lanes x 16B = 1024B contiguous run.
#define PHASE_S(MC, BUF) do {                                                     \
    _Pragma("unroll")                                                             \
    for (int i = 0; i < 8; ++i) {                                                 \
        const int row   = (i << 2) | w;                                           \
        const int rbase = ((row & 15) << 9) + ((row >> 4) << 13);                 \
        const uint2 rv  = *(const uint2*)((BUF) + rbase                           \
                                          + ((l << 3) ^ ((row & 7) << 4)));       \
        f32x4 fv;                                                                 \
        fv[0] = bf2f_lo(rv.x); fv[1] = bf2f_hi(rv.x);                             \
        fv[2] = bf2f_lo(rv.y); fv[3] = bf2f_hi(rv.y);                             \
        __builtin_nontemporal_store(fv,                                           \
            (f32x4*)(abase + (size_t)row * NPIX + ((MC) << 8)));                  \
    }                                                                             \
} while (0)

    PHASE_A(0, psb0);
    LDS_BARRIER();
    #pragma unroll 2
    for (int mc = 0; mc < 16; ++mc) {
        char* cur = (mc & 1) ? psb1 : psb0;
        char* nxt = (mc & 1) ? psb0 : psb1;
        if (mc < 15) PHASE_A(mc + 1, nxt);
        PHASE_B(mc, cur);
        PHASE_S(mc, cur);
        LDS_BARRIER();
    }
#undef PHASE_A
#undef PHASE_B
#undef PHASE_S

    // ---- epilogue: O_lds + LN scalars alias psb0 (dead after last barrier) ----
    float* O_lds = (float*)psb0;                   // [64][33] = 8448 B
    float* muv   = (float*)(psb0 + 8448);          // [32]
    float* rsg   = (float*)(psb0 + 8576);          // [32]
    {
        const int ch = (w << 4) + c16;
        const int r0 = g << 2;
        #pragma unroll
        for (int r = 0; r < 4; ++r) {
            O_lds[ch * 33 + r0 + r]      = acc0[r];
            O_lds[ch * 33 + 16 + r0 + r] = acc1[r];
        }
    }
    __syncthreads();

    const float gma = gamma_p[0];
    const float* xb = x + (size_t)b * CCH * NPIX + n0;
    {
        const int r = t >> 3, l8 = t & 7;
        float sum = 0.f, sum2 = 0.f;
        #pragma unroll
        for (int cc = 0; cc < 8; ++cc) {
            const int c = l8 + (cc << 3);
            const float pre = xb[(size_t)c * NPIX + r] + gma * O_lds[c * 33 + r];
            sum += pre; sum2 += pre * pre;
        }
        #pragma unroll
        for (int off = 1; off < 8; off <<= 1) {
            sum  += __shfl_xor(sum, off);
            sum2 += __shfl_xor(sum2, off);
        }
        if (l8 == 0) {
            const float m_ = sum * (1.f / 64.f);
            const float v_ = sum2 * (1.f / 64.f) - m_ * m_;
            muv[r] = m_;
            rsg[r] = rsqrtf(v_ + 1e-5f);
        }
    }
    __syncthreads();

    #pragma unroll
    for (int ii = 0; ii < 8; ++ii) {
        const int idx = t + (ii << 8);             // 0..2047 = 64c x 32n
        const int c = idx >> 5, nl = idx & 31;
        const float o   = O_lds[c * 33 + nl];
        const float fdv = gma * o;
        const float pre = xb[(size_t)c * NPIX + nl] + fdv;
        const float y   = (pre - muv[nl]) * rsg[nl] * ln_w[c] + ln_b[c];
        const size_t off = (size_t)b * CCH * NPIX + (size_t)c * NPIX + n0 + nl;
        ao_out[off] = o;
        fd_out[off] = fdv;
        out[off]    = y;
    }
}

extern "C" void kernel_launch(void* const* d_in, const int* in_sizes, int n_in,
                              void* d_out, int out_size, void* d_ws, size_t ws_size,
                              hipStream_t stream) {
    const float* x     = (const float*)d_in[0];
    const float* Wq    = (const float*)d_in[1];
    const float* bq    = (const float*)d_in[2];
    const float* Wk    = (const float*)d_in[3];
    const float* bk    = (const float*)d_in[4];
    const float* Wv    = (const float*)d_in[5];
    const float* bv    = (const float*)d_in[6];
    const float* gamma = (const float*)d_in[7];
    const float* lnw   = (const float*)d_in[8];
    const float* lnb   = (const float*)d_in[9];

    float* out  = (float*)d_out;                  // [8,64,64,64]
    float* attn = out + 2097152;                  // [8,4096,4096]
    float* fd   = out + 136314880;                // [8,64,64,64]
    float* ao   = out + 138412032;                // [8,64,64,64]
    unsigned short* ws = (unsigned short*)d_ws;   // 5 MB used

    qkv_kernel<<<2048, 256, 0, stream>>>(x, Wq, bq, Wk, bk, Wv, bv, ws);
    attn_kernel<<<1024, 256, 0, stream>>>(x, ws, gamma, lnw, lnb, out, attn, fd, ao);
}